// Round 18
// baseline (161.154 us; speedup 1.0000x reference)
//
#include <hip/hip_runtime.h>
#include <stdint.h>

// VectorQuantizer — z:(16,256,64,64) f32 -> 65536 rows of 256; emb:(1024,256) f32.
// d_out: q[16777216] | vq_loss[1] | idx_as_float[65536]
//
// R18: kill the ds_read->MFMA lgkm stall. R15/R16/R17 all pinned at ~113us with
// MfmaUtil 41% despite LDS/VALU/occupancy changes -> the per-iteration
// ds_read-consumed-immediately pattern (lgkmcnt(0) before every MFMA half,
// ~240cy/pair) is the prime suspect. B-fragments now register-double-buffered
// one K-step ahead; acc 64->32 (1 codetile/pass, 4 passes) pays the VGPR bill
// (32+16+32+~25 ~= 105 < 128 cap). T5 setprio around the MFMA cluster.
// Per-acc MFMA product order unchanged (eh*zh, eh*zl, el*zh) -> same numerics.

typedef __attribute__((ext_vector_type(8))) short short8;
typedef __attribute__((ext_vector_type(16))) float f32x16;

#define THR_S 1e-3f     // s-space margin threshold (= 2e-3 in dist space)
#define WLCAP 16384

__device__ __forceinline__ unsigned short f2bf(float f) {
    const unsigned int x = __float_as_uint(f);
    return (unsigned short)((x + 0x7FFFu + ((x >> 16) & 1u)) >> 16);
}
__device__ __forceinline__ float bf2f(unsigned short h) {
    return __uint_as_float(((unsigned int)h) << 16);
}

#define MFMA32(A, B, C) __builtin_amdgcn_mfma_f32_32x32x16_bf16(A, B, C, 0, 0, 0)

// ---------------- kernel 0: e prep — transpose-split codebook + norms ----------
__global__ __launch_bounds__(256)
void eprep_kernel(const float* __restrict__ emb, unsigned short* __restrict__ eh_t,
                  unsigned short* __restrict__ el_t, float* __restrict__ enorm,
                  int* __restrict__ wlcnt) {
    const int code = blockIdx.x;
    const int k = threadIdx.x;
    if (code == 0 && k == 0) wlcnt[0] = 0;
    const float v = emb[code * 256 + k];
    const unsigned short h = f2bf(v);
    const int idx = ((k >> 4) << 14) + (code << 4) + (((k >> 3) & 1) << 3) + (k & 7);
    eh_t[idx] = h;
    el_t[idx] = f2bf(v - bf2f(h));
    float s = v * v;
#pragma unroll
    for (int o = 32; o > 0; o >>= 1) s += __shfl_xor(s, o);
    __shared__ float red[4];
    if ((k & 63) == 0) red[k >> 6] = s;
    __syncthreads();
    if (k == 0) enorm[code] = (red[0] + red[1]) + (red[2] + red[3]);
}

// ---------------- kernel 1: MFMA argmin + fused gather/loss ----------------
#define UPD(S, C, B1, I1, B2) { \
    const bool lt_ = (S) < B1; \
    B2 = lt_ ? B1 : fminf(B2, (S)); \
    I1 = lt_ ? (C) : I1; \
    B1 = lt_ ? (S) : B1; }

#define MERGE32(B1, I1, B2) { \
    const float ob1_ = __shfl_xor(B1, 32); \
    const int   oi1_ = __shfl_xor(I1, 32); \
    const float ob2_ = __shfl_xor(B2, 32); \
    const float nb2_ = fminf(fminf(B2, ob2_), fmaxf(B1, ob1_)); \
    if (ob1_ < B1 || (ob1_ == B1 && oi1_ < I1)) { B1 = ob1_; I1 = oi1_; } \
    B2 = nb2_; }

#define PFLD(PH, PL, CT, KS) { \
    const int ofs_ = ((KS) << 15) + ((CT) << 10); \
    PH = *reinterpret_cast<const short8*>(ehp + ofs_); \
    PL = *reinterpret_cast<const short8*>(elp + ofs_); }

// 4 ds_read_b128 for one K-step's z fragments (both rowtiles, hi+lo)
#define LDB(H0, L0, H1, L1, KS) { \
    const int ko_ = (((KS) << 5) + (hi << 4)) ^ rsw; \
    H0 = *reinterpret_cast<const short8*>(zbuf + rb0 + ko_); \
    L0 = *reinterpret_cast<const short8*>(zbuf + 32768 + rb0 + ko_); \
    H1 = *reinterpret_cast<const short8*>(zbuf + rb1 + ko_); \
    L1 = *reinterpret_cast<const short8*>(zbuf + 32768 + rb1 + ko_); }

// 6 MFMA for one K-step; per-acc product order: eh*zh, eh*zl, el*zh (as R15-17)
#define MFMA6(PH, PL, H0, L0, H1, L1) \
    __builtin_amdgcn_s_setprio(1); \
    acc0 = MFMA32(PH, H0, acc0); \
    acc1 = MFMA32(PH, H1, acc1); \
    acc0 = MFMA32(PH, L0, acc0); \
    acc1 = MFMA32(PH, L1, acc1); \
    acc0 = MFMA32(PL, H0, acc0); \
    acc1 = MFMA32(PL, H1, acc1); \
    __builtin_amdgcn_s_setprio(0);

__global__ __launch_bounds__(512, 4)
void argmin_kernel(const float* __restrict__ z, const unsigned short* __restrict__ eh_t,
                   float* __restrict__ idx_out, int* __restrict__ wl,
                   int* __restrict__ wlcnt, const float* __restrict__ emb,
                   float* __restrict__ q_out, float* __restrict__ partials) {
    __shared__ char zbuf[65536];          // zh 32K | zl 32K: byte = row*512 + (2k ^ ((row&7)<<4))
    __shared__ float m_b1[8][64];
    __shared__ int   m_i1[8][64];
    __shared__ float m_b2[8][64];
    __shared__ int   fidx_s[64];

    const int t = threadIdx.x;
    const int l = t & 63;
    const int w = t >> 6;
    const int cl = l & 31;
    const int hi = l >> 5;

    const float* zblk = z + (size_t)blockIdx.x * 16384;

    // ---- stage z: fp32 -> bf16 hi/lo into swizzled LDS (once) ----
#pragma unroll
    for (int i = 0; i < 8; ++i) {
        const int idx = i * 2048 + t * 4;
        const int row = idx >> 8, k = idx & 255;
        const float4 v = *reinterpret_cast<const float4*>(zblk + idx);
        ushort4 hv, lv;
        hv.x = f2bf(v.x); lv.x = f2bf(v.x - bf2f(hv.x));
        hv.y = f2bf(v.y); lv.y = f2bf(v.y - bf2f(hv.y));
        hv.z = f2bf(v.z); lv.z = f2bf(v.z - bf2f(hv.z));
        hv.w = f2bf(v.w); lv.w = f2bf(v.w - bf2f(hv.w));
        const int boff = row * 512 + ((k << 1) ^ ((row & 7) << 4));
        *reinterpret_cast<ushort4*>(zbuf + boff) = hv;
        *reinterpret_cast<ushort4*>(zbuf + 32768 + boff) = lv;
    }
    __syncthreads();

    const char* ehp = (const char*)eh_t + (w * 128 + cl) * 32 + hi * 16;
    const char* elp = ehp + 524288;

    const int rb0 = cl * 512;
    const int rb1 = rb0 + 16384;
    const int rsw = (cl & 7) << 4;

    float b1a = 3.4e38f, b2a = 3.4e38f, b1b = 3.4e38f, b2b = 3.4e38f;
    int   i1a = 0, i1b = 0;

    short8 pfAh, pfAl, pfBh, pfBl;                       // A-frag: cur(even)/cur(odd)
    short8 ch0, cl0, ch1, cl1, nh0, nl0, nh1, nl1;       // B-frag cur / next

#pragma unroll 1
    for (int ct = 0; ct < 4; ++ct) {
        f32x16 acc0, acc1;   // rowtile 0 / 1
#pragma unroll
        for (int j = 0; j < 16; ++j) { acc0[j] = 0.f; acc1[j] = 0.f; }

        PFLD(pfAh, pfAl, ct, 0)
        LDB(ch0, cl0, ch1, cl1, 0)
        PFLD(pfBh, pfBl, ct, 1)

#pragma unroll 1
        for (int ks = 0; ks < 16; ks += 2) {
            // even step: compute ks with (pfA, c*); prefetch b @ks+1, A @ks+2
            LDB(nh0, nl0, nh1, nl1, ks + 1)
            MFMA6(pfAh, pfAl, ch0, cl0, ch1, cl1)
            if (ks < 14) PFLD(pfAh, pfAl, ct, ks + 2)
            // odd step: compute ks+1 with (pfB, n*); prefetch b @ks+2, A @ks+3
            if (ks < 14) LDB(ch0, cl0, ch1, cl1, ks + 2)
            MFMA6(pfBh, pfBl, nh0, nl0, nh1, nl1)
            if (ks < 14) PFLD(pfBh, pfBl, ct, ks + 3)
        }

        // ---- codetile epilogue: s = -dot, fold into running (b1, i1, b2) ----
        const int code0 = w * 128 + (ct << 5) + (hi << 2);
#pragma unroll
        for (int reg = 0; reg < 16; ++reg) {
            const int co = (reg & 3) + ((reg >> 2) << 3);
            const int c = code0 + co;
            UPD(-acc0[reg], c, b1a, i1a, b2a)
            UPD(-acc1[reg], c, b1b, i1b, b2b)
        }
    }

    MERGE32(b1a, i1a, b2a)
    MERGE32(b1b, i1b, b2b)
    if (l < 32) {
        m_b1[w][cl] = b1a;      m_i1[w][cl] = i1a;      m_b2[w][cl] = b2a;
        m_b1[w][cl + 32] = b1b; m_i1[w][cl + 32] = i1b; m_b2[w][cl + 32] = b2b;
    }
    __syncthreads();
    if (t < 64) {
        float b1 = m_b1[0][t]; int i1 = m_i1[0][t]; float b2 = m_b2[0][t];
#pragma unroll
        for (int g = 1; g < 8; ++g) {
            const float ob1 = m_b1[g][t]; const int oi1 = m_i1[g][t]; const float ob2 = m_b2[g][t];
            const float nb2 = fminf(fminf(b2, ob2), fmaxf(b1, ob1));
            if (ob1 < b1 || (ob1 == b1 && oi1 < i1)) { b1 = ob1; i1 = oi1; }
            b2 = nb2;
        }
        const int grow = blockIdx.x * 64 + t;
        idx_out[grow] = (float)i1;
        fidx_s[t] = i1;
        if (b2 - b1 < THR_S) {
            const int pos = atomicAdd(wlcnt, 1);
            if (pos < WLCAP) wl[pos] = grow;
        }
    }

    // ---- fused gather + loss partial (skipped in fallback mode) ----
    if (q_out != nullptr) {
        __syncthreads();   // fidx_s visible
        float lsum = 0.f;
        float* qblk = q_out + (size_t)blockIdx.x * 16384;
#pragma unroll
        for (int i = 0; i < 8; ++i) {
            const int row = i * 8 + w;     // wave w handles row i*8+w (uniform)
            const int code = fidx_s[row];
            const float4 e4 = *reinterpret_cast<const float4*>(
                emb + (size_t)code * 256 + l * 4);
            const int byt = row * 512 + ((l * 8) ^ ((row & 7) << 4));
            const ushort4 h4 = *reinterpret_cast<const ushort4*>(zbuf + byt);
            const ushort4 l4 = *reinterpret_cast<const ushort4*>(zbuf + 32768 + byt);
            const float zx = bf2f(h4.x) + bf2f(l4.x);
            const float zy = bf2f(h4.y) + bf2f(l4.y);
            const float zz = bf2f(h4.z) + bf2f(l4.z);
            const float zw = bf2f(h4.w) + bf2f(l4.w);
            const float dx = e4.x - zx, dy = e4.y - zy, dz = e4.z - zz, dw = e4.w - zw;
            lsum += dx * dx + dy * dy + dz * dz + dw * dw;
            *reinterpret_cast<float4*>(qblk + row * 256 + l * 4) = e4;
        }
#pragma unroll
        for (int o = 32; o > 0; o >>= 1) lsum += __shfl_xor(lsum, o);
        if (l == 0) m_b1[0][w] = lsum;    // reuse merge LDS as scratch
        __syncthreads();
        if (t == 0) {
            float s = 0.f;
#pragma unroll
            for (int g = 0; g < 8; ++g) s += m_b1[0][g];
            partials[blockIdx.x] = s;
        }
    }
}

// ---------------- kernel 2: exact fp32 fixup (+ q patch, loss delta) ----------
__global__ __launch_bounds__(256)
void fixup_kernel(const float* __restrict__ z, const float* __restrict__ emb,
                  const float* __restrict__ enorm_g, const int* __restrict__ wl,
                  const int* __restrict__ wlcnt, float* __restrict__ idx_out,
                  float* __restrict__ q_out, float* __restrict__ wl_delta) {
    __shared__ float zrow[256];
    __shared__ float znred[4];
    __shared__ float mb[4];
    __shared__ int   mi[4];
    __shared__ int   fin_s;
    __shared__ float dred[4];

    const int t = threadIdx.x;
    const int l = t & 63, wv = t >> 6;
    const int dq = l & 3, tx = (l >> 2) & 15;

    int n = wlcnt[0];
    if (n > WLCAP) n = WLCAP;

#pragma unroll 1
    for (int i = blockIdx.x; i < n; i += 256) {
        const int r = wl[i];
        const float v = z[(size_t)r * 256 + t];
        zrow[t] = v;
        float zn = v * v;
#pragma unroll
        for (int o = 32; o > 0; o >>= 1) zn += __shfl_xor(zn, o);
        if (l == 0) znred[wv] = zn;
        __syncthreads();
        const float znf = (znred[0] + znred[1]) + (znred[2] + znred[3]);

        float b1 = 3.4e38f;
        int   i1 = 0;
#pragma unroll 1
        for (int cc = 0; cc < 16; ++cc) {
            const int c = wv * 256 + cc * 16 + tx;
            const float* er = emb + (size_t)c * 256 + dq * 4;
            float dot = 0.f;
#pragma unroll
            for (int j = 0; j < 16; ++j) {
                const float4 ev = *reinterpret_cast<const float4*>(er + j * 16);
                const float4 zv = *reinterpret_cast<const float4*>(&zrow[j * 16 + dq * 4]);
                dot = fmaf(zv.x, ev.x, dot);
                dot = fmaf(zv.y, ev.y, dot);
                dot = fmaf(zv.z, ev.z, dot);
                dot = fmaf(zv.w, ev.w, dot);
            }
            dot += __shfl_xor(dot, 1);
            dot += __shfl_xor(dot, 2);
            const float dist = fmaf(-2.f, dot, znf + enorm_g[c]);
            if (dist < b1) { b1 = dist; i1 = c; }
        }
#pragma unroll
        for (int off = 4; off < 64; off <<= 1) {
            const float ov = __shfl_xor(b1, off);
            const int   oi = __shfl_xor(i1, off);
            if (ov < b1 || (ov == b1 && oi < i1)) { b1 = ov; i1 = oi; }
        }
        if (l == 0) { mb[wv] = b1; mi[wv] = i1; }
        __syncthreads();
        if (t == 0) {
            float fb = mb[0]; int fi = mi[0];
#pragma unroll
            for (int g = 1; g < 4; ++g)
                if (mb[g] < fb || (mb[g] == fb && mi[g] < fi)) { fb = mb[g]; fi = mi[g]; }
            fin_s = fi;
        }
        __syncthreads();
        const int fi = fin_s;
        if (wl_delta != nullptr) {
            const int oldi = (int)idx_out[r];
            float d = 0.f;
            if (fi != oldi) {
                const float en_ = emb[(size_t)fi * 256 + t];
                const float eo_ = emb[(size_t)oldi * 256 + t];
                const float zt = zrow[t];
                d = (en_ - zt) * (en_ - zt) - (eo_ - zt) * (eo_ - zt);
                q_out[(size_t)r * 256 + t] = en_;
            }
#pragma unroll
            for (int o = 32; o > 0; o >>= 1) d += __shfl_xor(d, o);
            if (l == 0) dred[wv] = d;
            __syncthreads();
            if (t == 0) {
                wl_delta[i] = (dred[0] + dred[1]) + (dred[2] + dred[3]);
                idx_out[r] = (float)fi;
            }
        } else {
            if (t == 0) idx_out[r] = (float)fi;
        }
        __syncthreads();   // LDS reused next iteration
    }
}

// ---------------- kernel 3 (fused path): loss = partials + deltas -------------
__global__ __launch_bounds__(256)
void loss_kernel(const float* __restrict__ partials, const float* __restrict__ wl_delta,
                 const int* __restrict__ wlcnt, float* __restrict__ loss_out) {
    const int tid = threadIdx.x;
    float s = partials[tid] + partials[tid + 256] + partials[tid + 512] + partials[tid + 768];
    int n = wlcnt[0];
    if (n > WLCAP) n = WLCAP;
    for (int i = tid; i < n; i += 256) s += wl_delta[i];
#pragma unroll
    for (int off = 32; off > 0; off >>= 1) s += __shfl_xor(s, off);
    __shared__ float red[4];
    if ((tid & 63) == 0) red[tid >> 6] = s;
    __syncthreads();
    if (tid == 0)
        loss_out[0] = ((red[0] + red[1]) + (red[2] + red[3])) * (1.25f / 16777216.0f);
}

// ---------------- fallback kernels (R13 flow, if ws too small) ----------------
__global__ __launch_bounds__(256)
void gather_kernel(const float* __restrict__ z, const float* __restrict__ emb,
                   const float* __restrict__ idx_f, float* __restrict__ q_out,
                   float* __restrict__ partials) {
    const int wv = threadIdx.x >> 6, ln = threadIdx.x & 63;
    float lsum = 0.f;
#pragma unroll
    for (int i = 0; i < 8; ++i) {
        const size_t row = (size_t)blockIdx.x * 32 + i * 4 + wv;
        const int kidx = (int)idx_f[row];
        const float4 e4 = *reinterpret_cast<const float4*>(emb + (size_t)kidx * 256 + ln * 4);
        const float4 z4 = *reinterpret_cast<const float4*>(z + row * 256 + ln * 4);
        *reinterpret_cast<float4*>(q_out + row * 256 + ln * 4) = e4;
        const float dx = e4.x - z4.x, dy = e4.y - z4.y, dz = e4.z - z4.z, dw = e4.w - z4.w;
        lsum += dx * dx + dy * dy + dz * dz + dw * dw;
    }
#pragma unroll
    for (int off = 32; off > 0; off >>= 1) lsum += __shfl_xor(lsum, off);
    __shared__ float red[4];
    if (ln == 0) red[wv] = lsum;
    __syncthreads();
    if (threadIdx.x == 0) partials[blockIdx.x] = red[0] + red[1] + red[2] + red[3];
}

__global__ __launch_bounds__(256)
void loss_fb_kernel(const float* __restrict__ partials, float* __restrict__ loss_out) {
    const int tid = threadIdx.x;
    float s = 0.f;
#pragma unroll
    for (int i = 0; i < 8; ++i) s += partials[tid + i * 256];
#pragma unroll
    for (int off = 32; off > 0; off >>= 1) s += __shfl_xor(s, off);
    __shared__ float red[4];
    if ((tid & 63) == 0) red[tid >> 6] = s;
    __syncthreads();
    if (tid == 0)
        loss_out[0] = (red[0] + red[1] + red[2] + red[3]) * (1.25f / 16777216.0f);
}

extern "C" void kernel_launch(void* const* d_in, const int* in_sizes, int n_in,
                              void* d_out, int out_size, void* d_ws, size_t ws_size,
                              hipStream_t stream) {
    const float* z   = (const float*)d_in[0];
    const float* emb = (const float*)d_in[1];
    float* out      = (float*)d_out;
    float* q_out    = out;                       // 16,777,216 floats
    float* loss_out = out + 16777216;            // 1 float
    float* idx_out  = out + 16777217;            // 65,536 floats

    // ws layout (floats): eh_t[131072] | el_t[131072] | enorm[1024] | partials[2048]
    //                     | wlcnt[64-pad] | wl[16384] | wl_delta[16384]
    const size_t WS_NEEDED = (size_t)298048 * 4;
    float* ws = (float*)d_ws;

    if (ws_size >= WS_NEEDED) {
        unsigned short* eh_t = (unsigned short*)ws;
        unsigned short* el_t = eh_t + 262144;
        float* enorm    = ws + 262144;
        float* partials = ws + 263168;
        int*   wlcnt    = (int*)(ws + 265216);
        int*   wl       = (int*)(ws + 265280);
        float* wl_delta = ws + 281664;

        eprep_kernel<<<1024, 256, 0, stream>>>(emb, eh_t, el_t, enorm, wlcnt);
        argmin_kernel<<<1024, 512, 0, stream>>>(z, eh_t, idx_out, wl, wlcnt,
                                                emb, q_out, partials);
        fixup_kernel<<<256, 256, 0, stream>>>(z, emb, enorm, wl, wlcnt, idx_out,
                                              q_out, wl_delta);
        loss_kernel<<<1, 256, 0, stream>>>(partials, wl_delta, wlcnt, loss_out);
    } else {
        // fallback: R13 flow, codebook scratch inside q (rewritten by gather)
        unsigned short* eh_t = (unsigned short*)q_out;
        unsigned short* el_t = eh_t + 262144;
        int*   wl    = (int*)(q_out + 262144);
        int*   wlcnt = (int*)(q_out + 327680);
        float* enorm    = ws;            // 1024
        float* partials = ws + 1024;     // 2048

        eprep_kernel<<<1024, 256, 0, stream>>>(emb, eh_t, el_t, enorm, wlcnt);
        argmin_kernel<<<1024, 512, 0, stream>>>(z, eh_t, idx_out, wl, wlcnt,
                                                emb, nullptr, nullptr);
        fixup_kernel<<<256, 256, 0, stream>>>(z, emb, enorm, wl, wlcnt, idx_out,
                                              nullptr, nullptr);
        gather_kernel<<<2048, 256, 0, stream>>>(z, emb, idx_out, q_out, partials);
        loss_fb_kernel<<<1, 256, 0, stream>>>(partials, loss_out);
    }
}